// Round 11
// baseline (196.108 us; speedup 1.0000x reference)
//
#include <hip/hip_runtime.h>
#include <math.h>

// Problem constants
#define Tn 30
#define Bn 16384
#define Hn 100
#define Pn 7

// Tiling: gates padded 100->128 units => N=512 (32 n-tiles); K padded 100->128 (4 k-tiles of 32).
// K slots 100/101 carry the FC1 fold: A[k=100]=x_t(row), A[k=101]=1.0; Whh1 B rows 100/101 hold
// u1[j]/wc1[j]; Wih2 row 101 holds bih2+bhh2; W2(ps=6) row 101 holds b2.
// Gate weights pre-scaled by log2e (gate g by 2*log2e, W2/b2 by log2e): activations use bare
// v_exp_f32 (exp2) with src-modifier negation.
// ROUND-11: (a) both row-groups' af loaded up front, 32 contiguous MFMAs (af1 latency hides
// under burst0), then both epilogues adjacent -> 8 independent trans chains per section;
// (b) cc rcp merged: cc = [c*d1 + s*t3]/(t3*d1), d1=(1+ei)(1+eg), t3=1+ef, with the 2log2e
// scale folded into s = fma(2log2e, eg, -2log2e) -> cst carried in exp2 units, ec = e2(cc).
// Trans/element 8 -> 7, one less mul. Peak arch live ~60 < 64 cap (WRITE_SIZE = spill tripwire).
// 32 rows/block (grid 512), 8 waves; wave w<7 owns units [16w,16w+16); wave 7 maintains K-slots
// in phase 1 and runs FC2 in phase 2. __launch_bounds__(512,4): 128 total regs/wave (64 arch +
// 64 acc for bf frags) => 2 blocks/CU = 4 waves/SIMD (register-file ceiling: 16 waves/CU).
#define ROWS 32           // rows per block
#define RGn 2             // row-groups of 16
#define KP 136            // h row pitch (ushorts); 272B -> 16B-aligned A-frag reads
#define RP 36             // gin2 row pitch (ushorts): 32 rows + 4 pad
#define NFRAG 128         // B-frags per matrix (32 nt x 4 kt)
#define FRAG_BYTES (NFRAG * 64 * 16)   // 131072 per matrix
#define WS_W2_OFF (3 * FRAG_BYTES)     // 28 W2 frags (7 ps x 4 kt)
#define HBUF_USH (ROWS * KP)           // 4352
#define G2_USH (512 * RP)              // 18432
#define XL_USH_OFF (2 * HBUF_USH + G2_USH)            // 27136 ushorts
#define SMEM_BYTES (XL_USH_OFF * 2 + Tn * ROWS * 4)   // 54272 + 3840 = 58112

#define PACK_BLOCKS 103   // (3*128*64 + 28*64)/256 exactly

#define LOG2E 1.4426950408889634f
#define LOG2E2 2.8853900817779268f   // 2*log2e

typedef __attribute__((ext_vector_type(8))) short short8;   // 8 bf16 (4 VGPRs)
typedef __attribute__((ext_vector_type(4))) float floatx4;  // MFMA C/D

__device__ __forceinline__ float rcp_(float v) { return __builtin_amdgcn_rcpf(v); }
__device__ __forceinline__ float e2_(float v) { return __builtin_amdgcn_exp2f(v); }
__device__ __forceinline__ unsigned short f2bf(float v) {
    unsigned int u = __float_as_uint(v);
    return (unsigned short)((u + 0x7FFFu + ((u >> 16) & 1u)) >> 16);   // RNE
}
#define MFMA __builtin_amdgcn_mfma_f32_16x16x32_bf16

// Pack the 3 recurrent matrices (400x100) into bf16 B-frag layout (gates padded to 128 units),
// with the bias/FC1 folds in padded K rows, ALL PRE-SCALED: gates i,f,o by log2e; gate g (G==2)
// by 2*log2e; W2/b2 by log2e. Folds:
//   mat 0 (Whh1): k=100 -> u1[j] = Wih1[j,:]·W1 ; k=101 -> wc1[j] = Wih1[j,:]·b1 + bih1[j] + bhh1[j]
//   mat 1 (Wih2): k=101 -> bih2[j] + bhh2[j]
//   W2 frags:     k=101 && ps==6 -> b2[p]   (A k=101 is 1.0 every step; add bias exactly once)
// B[k][n]: n = lane&15, k = (lane>>4)*8 + jj  (16x16x32 bf16 B mapping, HW-verified).
__global__ void setup_kernel(const float* __restrict__ W1,
                             const float* __restrict__ b1,
                             const float* __restrict__ Wih1,
                             const float* __restrict__ bih1,
                             const float* __restrict__ bhh1,
                             const float* __restrict__ bih2,
                             const float* __restrict__ bhh2,
                             const float* __restrict__ Whh1,
                             const float* __restrict__ Wih2,
                             const float* __restrict__ Whh2,
                             const float* __restrict__ W2,
                             const float* __restrict__ b2,
                             float* __restrict__ ws) {
    int gid = blockIdx.x * 256 + threadIdx.x;   // 3*128*64 + 28*64 = 26368
    int lane = gid & 63;
    int l = lane & 15, q = lane >> 4;
    unsigned short hh[8];
    uint4 u;
    if (gid < 3 * NFRAG * 64) {
        int mat = gid / (NFRAG * 64);
        int f = (gid % (NFRAG * 64)) >> 6;
        int nt = f >> 2, kt = f & 3;
        int G = nt >> 3, ag = nt & 7;
        int j = ag * 16 + l;                    // unit within gate
        int row = G * Hn + (j < Hn ? j : 0);    // row of the 400-row weight matrices
        const float sG = (G == 2) ? LOG2E2 : LOG2E;   // exp2 pre-scale (g gate carries the 2x)
        const float* W = (mat == 0) ? Whh1 : (mat == 1) ? Wih2 : Whh2;
        const float* wrow = W + row * Hn;
        float u1 = 0.f, wc1 = 0.f;
        if (mat == 0 && kt == 3 && q == 0 && j < Hn) {   // lanes producing k=100/101
            for (int k = 0; k < Hn; ++k) {
                float a = Wih1[row * Hn + k];
                u1 += a * W1[k];
                wc1 += a * b1[k];
            }
            wc1 += bih1[row] + bhh1[row];
        }
        int kbase = kt * 32 + q * 8;
#pragma unroll
        for (int jj = 0; jj < 8; ++jj) {
            int k = kbase + jj;
            unsigned short v = 0;
            if (j < Hn) {
                if (k < Hn) v = f2bf(wrow[k] * sG);
                else if (mat == 0 && k == 100) v = f2bf(u1 * sG);
                else if (mat == 0 && k == 101) v = f2bf(wc1 * sG);
                else if (mat == 1 && k == 101) v = f2bf((bih2[row] + bhh2[row]) * sG);
            }
            hh[jj] = v;
        }
        u.x = (unsigned)hh[0] | ((unsigned)hh[1] << 16);
        u.y = (unsigned)hh[2] | ((unsigned)hh[3] << 16);
        u.z = (unsigned)hh[4] | ((unsigned)hh[5] << 16);
        u.w = (unsigned)hh[6] | ((unsigned)hh[7] << 16);
        ((uint4*)((char*)ws + mat * FRAG_BYTES))[f * 64 + lane] = u;
    } else {
        int t = gid - 3 * NFRAG * 64;           // 0..1791
        int f = t >> 6;                         // 0..27 = ps*4 + kt
        int ps = f >> 2, kt = f & 3;
        int kbase = kt * 32 + q * 8;
#pragma unroll
        for (int jj = 0; jj < 8; ++jj) {
            int k = kbase + jj;
            unsigned short v = 0;
            if (l < Pn) {
                if (k < Hn) v = f2bf(W2[l * (Pn * Hn) + ps * Hn + k] * LOG2E);
                else if (k == 101 && ps == 6) v = f2bf(b2[l] * LOG2E);
            }
            hh[jj] = v;
        }
        u.x = (unsigned)hh[0] | ((unsigned)hh[1] << 16);
        u.y = (unsigned)hh[2] | ((unsigned)hh[3] << 16);
        u.z = (unsigned)hh[4] | ((unsigned)hh[5] << 16);
        u.w = (unsigned)hh[6] | ((unsigned)hh[7] << 16);
        ((uint4*)((char*)ws + WS_W2_OFF))[f * 64 + lane] = u;
    }
}

__global__ __launch_bounds__(512, 4) void lstm_fused(
    const float* __restrict__ x,     // (T,B)
    const float* __restrict__ ws,    // packed frags (+folds), exp2-prescaled
    float* __restrict__ out)         // (B,7)
{
    extern __shared__ unsigned short sm[];
    unsigned short* hb0 = sm;                   // h double buffer [row ROWS][k KP]
    unsigned short* hb1 = sm + HBUF_USH;
    unsigned short* g2 = sm + 2 * HBUF_USH;     // gin2 bf16 [n 512][row RP] (scaled units)
    float* xl = (float*)(sm + XL_USH_OFF);      // x slice [t 30][row 32]

    const int tid = threadIdx.x;
    const int wave = tid >> 6, lane = tid & 63;
    const int l = lane & 15, q = lane >> 4;
    const int jcol = wave * 16 + l;             // this wave's unit column (0..127)
    const int rowbase = blockIdx.x * ROWS;
    // store predicate: waves 0-5 all-real; wave 6 must preserve cols 100/101 (x / 1.0 slots);
    // pad cols 102..111 take hv which is exactly 0 there (zero B cols -> zero preacts).
    const bool wr = (wave != 6) || (l < 4) || (l >= 6);

    for (int i = tid; i < 2 * HBUF_USH; i += 512) sm[i] = 0;
    for (int i = tid; i < Tn * ROWS; i += 512)
        xl[i] = x[(i >> 5) * Bn + rowbase + (i & 31)];
    __syncthreads();   // zeroing + x staging done before seeding
    if (tid < ROWS) {
        hb0[tid * KP + 100] = f2bf(x[rowbase + tid]);   // x_0 in K slot 100
        hb0[tid * KP + 101] = (unsigned short)0x3F80;   // 1.0 in K slot 101
    }

    // this wave's 16 Whh1 B-frags -> registers (held for all 30 steps; AGPR-resident)
    short8 bf[4][4];   // [G][kt]
    floatx4 cst[RGn];  // cell state (in 2log2e/exp2 units), rows 4q+r, unit jcol
    const floatx4 zro = (floatx4){0.f, 0.f, 0.f, 0.f};
    if (wave < 7) {
        const short8* fr = (const short8*)ws;
#pragma unroll
        for (int G = 0; G < 4; ++G)
#pragma unroll
            for (int kt = 0; kt < 4; ++kt)
                bf[G][kt] = fr[((((G << 3) | wave) << 2) + kt) * 64 + lane];
#pragma unroll
        for (int rg = 0; rg < RGn; ++rg) cst[rg] = zro;
    }
    __syncthreads();   // h buffers ready (zero + seed)

    // Epilogue: gates exp2-scaled (i',f',o' = v*log2e; g' = v*2log2e). Merged-rcp cell update:
    // sig(f)*c + sig(i)tanh(g) = [c*d1 + s*t3] / (t3*d1), d1=(1+ei)(1+eg), t3=1+ef,
    // s=2log2e*(eg-1) so cst is in exp2 units and ec = e2(cc) directly. 7 trans/element.
    auto epi = [&](const floatx4& Gi, const floatx4& Gf, const floatx4& Gg,
                   const floatx4& Go, int rg, unsigned short* hn) {
#pragma unroll
        for (int r = 0; r < 4; ++r) {
            float ei = e2_(-Gi[r]);
            float eg = e2_(Gg[r]);
            float ef = e2_(-Gf[r]);
            float t1 = 1.f + ei;
            float d1 = fmaf(t1, eg, t1);             // (1+ei)(1+eg)
            float t3 = 1.f + ef;
            float s  = fmaf(LOG2E2, eg, -LOG2E2);    // 2log2e*(eg-1)
            float num = fmaf(cst[rg][r], d1, s * t3);
            float cc = num * rcp_(t3 * d1);          // cell state, exp2 units
            cst[rg][r] = cc;
            float eo = e2_(-Go[r]);
            float ec = e2_(cc);
            float t2 = 1.f + eo;
            float hv = (ec - 1.f) * rcp_(fmaf(t2, ec, t2));
            if (wr)
                hn[(rg * 16 + 4 * q + r) * KP + jcol] = f2bf(hv);
        }
    };

    // ---- Phase 1: LSTM1, 30 steps, 1 barrier/step; t-loop unrolled x2 (fixed buffers) ----
    // Both rg's af loaded up front; 32 contiguous MFMAs; both epilogues adjacent (8 chains).
    auto cell1 = [&](const unsigned short* __restrict__ hc,
                     unsigned short* __restrict__ hn, int t) {
        if (wave == 7) {
            // K-slot maintenance: hn[.,100] = x_{t+1}, hn[.,101] = 1.0
            int tn = (t < Tn - 1) ? t + 1 : t;
            int row = lane & 31;
            float xv = xl[tn * ROWS + row];
            unsigned short val = (lane < 32) ? f2bf(xv) : (unsigned short)0x3F80;
            hn[row * KP + 100 + (lane >> 5)] = val;
        } else {
            short8 af0[4], af1[4];
#pragma unroll
            for (int kt = 0; kt < 4; ++kt) {
                af0[kt] = *(const short8*)(hc + l * KP + kt * 32 + q * 8);
                af1[kt] = *(const short8*)(hc + (16 + l) * KP + kt * 32 + q * 8);
            }
            floatx4 A0, A1, A2, A3;
            A0 = MFMA(af0[0], bf[0][0], zro, 0, 0, 0);
            A1 = MFMA(af0[0], bf[1][0], zro, 0, 0, 0);
            A2 = MFMA(af0[0], bf[2][0], zro, 0, 0, 0);
            A3 = MFMA(af0[0], bf[3][0], zro, 0, 0, 0);
#pragma unroll
            for (int kt = 1; kt < 4; ++kt) {
                A0 = MFMA(af0[kt], bf[0][kt], A0, 0, 0, 0);
                A1 = MFMA(af0[kt], bf[1][kt], A1, 0, 0, 0);
                A2 = MFMA(af0[kt], bf[2][kt], A2, 0, 0, 0);
                A3 = MFMA(af0[kt], bf[3][kt], A3, 0, 0, 0);
            }
            floatx4 B0, B1, B2, B3;
            B0 = MFMA(af1[0], bf[0][0], zro, 0, 0, 0);
            B1 = MFMA(af1[0], bf[1][0], zro, 0, 0, 0);
            B2 = MFMA(af1[0], bf[2][0], zro, 0, 0, 0);
            B3 = MFMA(af1[0], bf[3][0], zro, 0, 0, 0);
#pragma unroll
            for (int kt = 1; kt < 4; ++kt) {
                B0 = MFMA(af1[kt], bf[0][kt], B0, 0, 0, 0);
                B1 = MFMA(af1[kt], bf[1][kt], B1, 0, 0, 0);
                B2 = MFMA(af1[kt], bf[2][kt], B2, 0, 0, 0);
                B3 = MFMA(af1[kt], bf[3][kt], B3, 0, 0, 0);
            }
            epi(A0, A1, A2, A3, 0, hn);
            epi(B0, B1, B2, B3, 1, hn);
        }
    };
    for (int tt = 0; tt < Tn; tt += 2) {
        cell1(hb0, hb1, tt);
        __syncthreads();
        cell1(hb1, hb0, tt + 1);
        __syncthreads();
    }

    // ---- Wih2 frags; gin2 = (bih2+bhh2 fold) + last·Wih2^T parked in LDS (scaled units) ----
    if (wave < 7) {
        const short8* fr = (const short8*)((const char*)ws + FRAG_BYTES);
#pragma unroll
        for (int G = 0; G < 4; ++G)
#pragma unroll
            for (int kt = 0; kt < 4; ++kt)
                bf[G][kt] = fr[((((G << 3) | wave) << 2) + kt) * 64 + lane];
        const unsigned short* hl = hb0;   // last = h after t=29 (t=29 odd -> hn was hb0)
        // hl K-slots: 100 = stale x (Wih2 row 100 is zero -> harmless), 101 = 1.0 (bias fold)
#pragma unroll
        for (int rg = 0; rg < RGn; ++rg) {
            short8 af[4];
#pragma unroll
            for (int kt = 0; kt < 4; ++kt)
                af[kt] = *(const short8*)(hl + (rg * 16 + l) * KP + kt * 32 + q * 8);
            floatx4 acc[4];
#pragma unroll
            for (int G = 0; G < 4; ++G)
                acc[G] = MFMA(af[0], bf[G][0], zro, 0, 0, 0);
#pragma unroll
            for (int kt = 1; kt < 4; ++kt)
#pragma unroll
                for (int G = 0; G < 4; ++G)
                    acc[G] = MFMA(af[kt], bf[G][kt], acc[G], 0, 0, 0);
#pragma unroll
            for (int G = 0; G < 4; ++G) {
                int n = G * 128 + jcol;
                uint2 pk;
                pk.x = (unsigned)f2bf(acc[G][0]) | ((unsigned)f2bf(acc[G][1]) << 16);
                pk.y = (unsigned)f2bf(acc[G][2]) | ((unsigned)f2bf(acc[G][3]) << 16);
                *(uint2*)(g2 + n * RP + rg * 16 + 4 * q) = pk;   // same wave reads it back
            }
        }
        // ---- Whh2 frags ----
        const short8* fr2 = (const short8*)((const char*)ws + 2 * FRAG_BYTES);
#pragma unroll
        for (int G = 0; G < 4; ++G)
#pragma unroll
            for (int kt = 0; kt < 4; ++kt)
                bf[G][kt] = fr2[((((G << 3) | wave) << 2) + kt) * 64 + lane];
    }

    // ---- Phase 2: LSTM2, 7 steps; FC2 runs on wave 7 ----
    // K-slots 100/101 retain phase-1 values (101=1.0 feeds bias folds; 100=stale x hits zero
    // weight rows). Pad cols: zero preacts -> hv=0 (garbage-free as in phase 1).
    const short8* w2fr = (const short8*)((const char*)ws + WS_W2_OFF);
    floatx4 yfc[RGn];
    if (wave == 7) {
#pragma unroll
        for (int rg = 0; rg < RGn; ++rg) yfc[rg] = zro;
    }

    for (int ps = 0; ps < Pn; ++ps) {
        int t = Tn + ps;
        const unsigned short* hc = (t & 1) ? hb1 : hb0;
        unsigned short* hn = (t & 1) ? hb0 : hb1;
        if (wave == 7) {
            if (ps >= 1) {   // hc holds h2 of step ps-1
                short8 w2f[4];
#pragma unroll
                for (int kt = 0; kt < 4; ++kt)
                    w2f[kt] = w2fr[((ps - 1) * 4 + kt) * 64 + lane];
#pragma unroll
                for (int rg = 0; rg < RGn; ++rg) {
                    short8 af2[4];
#pragma unroll
                    for (int kt = 0; kt < 4; ++kt)
                        af2[kt] = *(const short8*)(hc + (rg * 16 + l) * KP + kt * 32 + q * 8);
#pragma unroll
                    for (int kt = 0; kt < 4; ++kt)
                        yfc[rg] = MFMA(af2[kt], w2f[kt], yfc[rg], 0, 0, 0);
                }
            }
        } else {
            short8 af0[4], af1[4];
#pragma unroll
            for (int kt = 0; kt < 4; ++kt) {
                af0[kt] = *(const short8*)(hc + l * KP + kt * 32 + q * 8);
                af1[kt] = *(const short8*)(hc + (16 + l) * KP + kt * 32 + q * 8);
            }
            floatx4 A0, A1, A2, A3;
            {   // C-in = gin2 (bias2 + last·Wih2^T), rg0
                uint2 p0 = *(const uint2*)(g2 + (0 * 128 + jcol) * RP + 4 * q);
                uint2 p1 = *(const uint2*)(g2 + (1 * 128 + jcol) * RP + 4 * q);
                uint2 p2 = *(const uint2*)(g2 + (2 * 128 + jcol) * RP + 4 * q);
                uint2 p3 = *(const uint2*)(g2 + (3 * 128 + jcol) * RP + 4 * q);
                A0[0] = __uint_as_float(p0.x << 16);
                A0[1] = __uint_as_float(p0.x & 0xFFFF0000u);
                A0[2] = __uint_as_float(p0.y << 16);
                A0[3] = __uint_as_float(p0.y & 0xFFFF0000u);
                A1[0] = __uint_as_float(p1.x << 16);
                A1[1] = __uint_as_float(p1.x & 0xFFFF0000u);
                A1[2] = __uint_as_float(p1.y << 16);
                A1[3] = __uint_as_float(p1.y & 0xFFFF0000u);
                A2[0] = __uint_as_float(p2.x << 16);
                A2[1] = __uint_as_float(p2.x & 0xFFFF0000u);
                A2[2] = __uint_as_float(p2.y << 16);
                A2[3] = __uint_as_float(p2.y & 0xFFFF0000u);
                A3[0] = __uint_as_float(p3.x << 16);
                A3[1] = __uint_as_float(p3.x & 0xFFFF0000u);
                A3[2] = __uint_as_float(p3.y << 16);
                A3[3] = __uint_as_float(p3.y & 0xFFFF0000u);
            }
#pragma unroll
            for (int kt = 0; kt < 4; ++kt) {
                A0 = MFMA(af0[kt], bf[0][kt], A0, 0, 0, 0);
                A1 = MFMA(af0[kt], bf[1][kt], A1, 0, 0, 0);
                A2 = MFMA(af0[kt], bf[2][kt], A2, 0, 0, 0);
                A3 = MFMA(af0[kt], bf[3][kt], A3, 0, 0, 0);
            }
            floatx4 B0, B1, B2, B3;
            {   // rg1
                uint2 p0 = *(const uint2*)(g2 + (0 * 128 + jcol) * RP + 16 + 4 * q);
                uint2 p1 = *(const uint2*)(g2 + (1 * 128 + jcol) * RP + 16 + 4 * q);
                uint2 p2 = *(const uint2*)(g2 + (2 * 128 + jcol) * RP + 16 + 4 * q);
                uint2 p3 = *(const uint2*)(g2 + (3 * 128 + jcol) * RP + 16 + 4 * q);
                B0[0] = __uint_as_float(p0.x << 16);
                B0[1] = __uint_as_float(p0.x & 0xFFFF0000u);
                B0[2] = __uint_as_float(p0.y << 16);
                B0[3] = __uint_as_float(p0.y & 0xFFFF0000u);
                B1[0] = __uint_as_float(p1.x << 16);
                B1[1] = __uint_as_float(p1.x & 0xFFFF0000u);
                B1[2] = __uint_as_float(p1.y << 16);
                B1[3] = __uint_as_float(p1.y & 0xFFFF0000u);
                B2[0] = __uint_as_float(p2.x << 16);
                B2[1] = __uint_as_float(p2.x & 0xFFFF0000u);
                B2[2] = __uint_as_float(p2.y << 16);
                B2[3] = __uint_as_float(p2.y & 0xFFFF0000u);
                B3[0] = __uint_as_float(p3.x << 16);
                B3[1] = __uint_as_float(p3.x & 0xFFFF0000u);
                B3[2] = __uint_as_float(p3.y << 16);
                B3[3] = __uint_as_float(p3.y & 0xFFFF0000u);
            }
#pragma unroll
            for (int kt = 0; kt < 4; ++kt) {
                B0 = MFMA(af1[kt], bf[0][kt], B0, 0, 0, 0);
                B1 = MFMA(af1[kt], bf[1][kt], B1, 0, 0, 0);
                B2 = MFMA(af1[kt], bf[2][kt], B2, 0, 0, 0);
                B3 = MFMA(af1[kt], bf[3][kt], B3, 0, 0, 0);
            }
            epi(A0, A1, A2, A3, 0, hn);
            epi(B0, B1, B2, B3, 1, hn);
        }
        __syncthreads();
    }

    // ---- final FC2 for h2 of ps=6 (t=36 even -> hn=hb1); b2 folded (scaled) into ps=6 k=101 ----
    if (wave == 7) {
        short8 w2f[4];
#pragma unroll
        for (int kt = 0; kt < 4; ++kt)
            w2f[kt] = w2fr[(6 * 4 + kt) * 64 + lane];
#pragma unroll
        for (int rg = 0; rg < RGn; ++rg) {
            short8 af2[4];
#pragma unroll
            for (int kt = 0; kt < 4; ++kt)
                af2[kt] = *(const short8*)(hb1 + (rg * 16 + l) * KP + kt * 32 + q * 8);
#pragma unroll
            for (int kt = 0; kt < 4; ++kt)
                yfc[rg] = MFMA(af2[kt], w2f[kt], yfc[rg], 0, 0, 0);
            if (l < Pn) {
#pragma unroll
                for (int r = 0; r < 4; ++r)   // y is log2e-scaled: sig = 1/(1+2^-y')
                    out[(rowbase + rg * 16 + 4 * q + r) * Pn + l] =
                        rcp_(1.f + e2_(-yfc[rg][r]));
            }
        }
    }
}

extern "C" void kernel_launch(void* const* d_in, const int* in_sizes, int n_in,
                              void* d_out, int out_size, void* d_ws, size_t ws_size,
                              hipStream_t stream) {
    const float* x    = (const float*)d_in[0];
    const float* W1   = (const float*)d_in[1];
    const float* b1   = (const float*)d_in[2];
    const float* Wih1 = (const float*)d_in[3];
    const float* Whh1 = (const float*)d_in[4];
    const float* bih1 = (const float*)d_in[5];
    const float* bhh1 = (const float*)d_in[6];
    const float* Wih2 = (const float*)d_in[7];
    const float* Whh2 = (const float*)d_in[8];
    const float* bih2 = (const float*)d_in[9];
    const float* bhh2 = (const float*)d_in[10];
    const float* W2   = (const float*)d_in[11];
    const float* b2   = (const float*)d_in[12];
    float* out = (float*)d_out;
    float* ws  = (float*)d_ws;

    (void)hipFuncSetAttribute((const void*)lstm_fused,
                              hipFuncAttributeMaxDynamicSharedMemorySize, SMEM_BYTES);

    setup_kernel<<<PACK_BLOCKS, 256, 0, stream>>>(W1, b1, Wih1, bih1, bhh1,
                                                  bih2, bhh2, Whh1, Wih2, Whh2, W2, b2, ws);
    lstm_fused<<<Bn / ROWS, 512, SMEM_BYTES, stream>>>(x, ws, out);
}

// Round 12
// 175.261 us; speedup vs baseline: 1.1190x; 1.1190x over previous
//
#include <hip/hip_runtime.h>
#include <math.h>

// Problem constants
#define Tn 30
#define Bn 16384
#define Hn 100
#define Pn 7

// Tiling: gates padded 100->128 units => N=512 (32 n-tiles); K padded 100->128 (4 k-tiles of 32).
// K slots 100/101 carry the FC1 fold: A[k=100]=x_t(row), A[k=101]=1.0; Whh1 B rows 100/101 hold
// u1[j]/wc1[j]; Wih2 row 101 holds bih2+bhh2; W2(ps=6) row 101 holds b2.
// Gate weights pre-scaled by log2e (gate g by 2*log2e, W2/b2 by log2e): bare v_exp_f32 (exp2)
// with src-modifier negation.
// ROUND-12: revert round-11's rg-merge (32-MFMA burst needed af0+af1+8 accs -> ~72 arch regs,
// blew the 64 cap: WRITE_SIZE 3->52 MB, 107->135 us). KEEP the merged-rcp cell update (validated
// bit-stable): cc = [c*d1 + s*t3]/(t3*d1), d1=(1+ei)(1+eg), t3=1+ef, s=fma(2log2e,eg,-2log2e),
// cst carried in exp2 units, ec=e2(cc) -> 7 trans/element. Chassis = round-10 (per-rg:
// load af, 16-MFMA burst with 4 independent chains, epilogue).
// Structural note: the 64-arch cap admits exactly ONE rg working set; 2 blocks/CU is the
// register-file ceiling (128 total/wave = 64 arch + 64 AGPR for bf frags).
#define ROWS 32           // rows per block
#define RGn 2             // row-groups of 16
#define KP 136            // h row pitch (ushorts); 272B -> 16B-aligned A-frag reads
#define RP 36             // gin2 row pitch (ushorts): 32 rows + 4 pad
#define NFRAG 128         // B-frags per matrix (32 nt x 4 kt)
#define FRAG_BYTES (NFRAG * 64 * 16)   // 131072 per matrix
#define WS_W2_OFF (3 * FRAG_BYTES)     // 28 W2 frags (7 ps x 4 kt)
#define HBUF_USH (ROWS * KP)           // 4352
#define G2_USH (512 * RP)              // 18432
#define XL_USH_OFF (2 * HBUF_USH + G2_USH)            // 27136 ushorts
#define SMEM_BYTES (XL_USH_OFF * 2 + Tn * ROWS * 4)   // 54272 + 3840 = 58112

#define PACK_BLOCKS 103   // (3*128*64 + 28*64)/256 exactly

#define LOG2E 1.4426950408889634f
#define LOG2E2 2.8853900817779268f   // 2*log2e

typedef __attribute__((ext_vector_type(8))) short short8;   // 8 bf16 (4 VGPRs)
typedef __attribute__((ext_vector_type(4))) float floatx4;  // MFMA C/D

__device__ __forceinline__ float rcp_(float v) { return __builtin_amdgcn_rcpf(v); }
__device__ __forceinline__ float e2_(float v) { return __builtin_amdgcn_exp2f(v); }
__device__ __forceinline__ unsigned short f2bf(float v) {
    unsigned int u = __float_as_uint(v);
    return (unsigned short)((u + 0x7FFFu + ((u >> 16) & 1u)) >> 16);   // RNE
}
#define MFMA __builtin_amdgcn_mfma_f32_16x16x32_bf16

// Pack the 3 recurrent matrices (400x100) into bf16 B-frag layout (gates padded to 128 units),
// with the bias/FC1 folds in padded K rows, ALL PRE-SCALED: gates i,f,o by log2e; gate g (G==2)
// by 2*log2e; W2/b2 by log2e. Folds:
//   mat 0 (Whh1): k=100 -> u1[j] = Wih1[j,:]·W1 ; k=101 -> wc1[j] = Wih1[j,:]·b1 + bih1[j] + bhh1[j]
//   mat 1 (Wih2): k=101 -> bih2[j] + bhh2[j]
//   W2 frags:     k=101 && ps==6 -> b2[p]   (A k=101 is 1.0 every step; add bias exactly once)
// B[k][n]: n = lane&15, k = (lane>>4)*8 + jj  (16x16x32 bf16 B mapping, HW-verified).
__global__ void setup_kernel(const float* __restrict__ W1,
                             const float* __restrict__ b1,
                             const float* __restrict__ Wih1,
                             const float* __restrict__ bih1,
                             const float* __restrict__ bhh1,
                             const float* __restrict__ bih2,
                             const float* __restrict__ bhh2,
                             const float* __restrict__ Whh1,
                             const float* __restrict__ Wih2,
                             const float* __restrict__ Whh2,
                             const float* __restrict__ W2,
                             const float* __restrict__ b2,
                             float* __restrict__ ws) {
    int gid = blockIdx.x * 256 + threadIdx.x;   // 3*128*64 + 28*64 = 26368
    int lane = gid & 63;
    int l = lane & 15, q = lane >> 4;
    unsigned short hh[8];
    uint4 u;
    if (gid < 3 * NFRAG * 64) {
        int mat = gid / (NFRAG * 64);
        int f = (gid % (NFRAG * 64)) >> 6;
        int nt = f >> 2, kt = f & 3;
        int G = nt >> 3, ag = nt & 7;
        int j = ag * 16 + l;                    // unit within gate
        int row = G * Hn + (j < Hn ? j : 0);    // row of the 400-row weight matrices
        const float sG = (G == 2) ? LOG2E2 : LOG2E;   // exp2 pre-scale (g gate carries the 2x)
        const float* W = (mat == 0) ? Whh1 : (mat == 1) ? Wih2 : Whh2;
        const float* wrow = W + row * Hn;
        float u1 = 0.f, wc1 = 0.f;
        if (mat == 0 && kt == 3 && q == 0 && j < Hn) {   // lanes producing k=100/101
            for (int k = 0; k < Hn; ++k) {
                float a = Wih1[row * Hn + k];
                u1 += a * W1[k];
                wc1 += a * b1[k];
            }
            wc1 += bih1[row] + bhh1[row];
        }
        int kbase = kt * 32 + q * 8;
#pragma unroll
        for (int jj = 0; jj < 8; ++jj) {
            int k = kbase + jj;
            unsigned short v = 0;
            if (j < Hn) {
                if (k < Hn) v = f2bf(wrow[k] * sG);
                else if (mat == 0 && k == 100) v = f2bf(u1 * sG);
                else if (mat == 0 && k == 101) v = f2bf(wc1 * sG);
                else if (mat == 1 && k == 101) v = f2bf((bih2[row] + bhh2[row]) * sG);
            }
            hh[jj] = v;
        }
        u.x = (unsigned)hh[0] | ((unsigned)hh[1] << 16);
        u.y = (unsigned)hh[2] | ((unsigned)hh[3] << 16);
        u.z = (unsigned)hh[4] | ((unsigned)hh[5] << 16);
        u.w = (unsigned)hh[6] | ((unsigned)hh[7] << 16);
        ((uint4*)((char*)ws + mat * FRAG_BYTES))[f * 64 + lane] = u;
    } else {
        int t = gid - 3 * NFRAG * 64;           // 0..1791
        int f = t >> 6;                         // 0..27 = ps*4 + kt
        int ps = f >> 2, kt = f & 3;
        int kbase = kt * 32 + q * 8;
#pragma unroll
        for (int jj = 0; jj < 8; ++jj) {
            int k = kbase + jj;
            unsigned short v = 0;
            if (l < Pn) {
                if (k < Hn) v = f2bf(W2[l * (Pn * Hn) + ps * Hn + k] * LOG2E);
                else if (k == 101 && ps == 6) v = f2bf(b2[l] * LOG2E);
            }
            hh[jj] = v;
        }
        u.x = (unsigned)hh[0] | ((unsigned)hh[1] << 16);
        u.y = (unsigned)hh[2] | ((unsigned)hh[3] << 16);
        u.z = (unsigned)hh[4] | ((unsigned)hh[5] << 16);
        u.w = (unsigned)hh[6] | ((unsigned)hh[7] << 16);
        ((uint4*)((char*)ws + WS_W2_OFF))[f * 64 + lane] = u;
    }
}

__global__ __launch_bounds__(512, 4) void lstm_fused(
    const float* __restrict__ x,     // (T,B)
    const float* __restrict__ ws,    // packed frags (+folds), exp2-prescaled
    float* __restrict__ out)         // (B,7)
{
    extern __shared__ unsigned short sm[];
    unsigned short* hb0 = sm;                   // h double buffer [row ROWS][k KP]
    unsigned short* hb1 = sm + HBUF_USH;
    unsigned short* g2 = sm + 2 * HBUF_USH;     // gin2 bf16 [n 512][row RP] (scaled units)
    float* xl = (float*)(sm + XL_USH_OFF);      // x slice [t 30][row 32]

    const int tid = threadIdx.x;
    const int wave = tid >> 6, lane = tid & 63;
    const int l = lane & 15, q = lane >> 4;
    const int jcol = wave * 16 + l;             // this wave's unit column (0..127)
    const int rowbase = blockIdx.x * ROWS;
    // store predicate: waves 0-5 all-real; wave 6 must preserve cols 100/101 (x / 1.0 slots);
    // pad cols 102..111 take hv which is exactly 0 there (zero B cols -> zero preacts).
    const bool wr = (wave != 6) || (l < 4) || (l >= 6);

    for (int i = tid; i < 2 * HBUF_USH; i += 512) sm[i] = 0;
    for (int i = tid; i < Tn * ROWS; i += 512)
        xl[i] = x[(i >> 5) * Bn + rowbase + (i & 31)];
    __syncthreads();   // zeroing + x staging done before seeding
    if (tid < ROWS) {
        hb0[tid * KP + 100] = f2bf(x[rowbase + tid]);   // x_0 in K slot 100
        hb0[tid * KP + 101] = (unsigned short)0x3F80;   // 1.0 in K slot 101
    }

    // this wave's 16 Whh1 B-frags -> registers (held for all 30 steps; AGPR-resident)
    short8 bf[4][4];   // [G][kt]
    floatx4 cst[RGn];  // cell state (exp2 units: cc = c * 2log2e), rows 4q+r, unit jcol
    const floatx4 zro = (floatx4){0.f, 0.f, 0.f, 0.f};
    if (wave < 7) {
        const short8* fr = (const short8*)ws;
#pragma unroll
        for (int G = 0; G < 4; ++G)
#pragma unroll
            for (int kt = 0; kt < 4; ++kt)
                bf[G][kt] = fr[((((G << 3) | wave) << 2) + kt) * 64 + lane];
#pragma unroll
        for (int rg = 0; rg < RGn; ++rg) cst[rg] = zro;
    }
    __syncthreads();   // h buffers ready (zero + seed)

    // Epilogue: gates exp2-scaled (i',f',o' = v*log2e; g' = v*2log2e). Merged-rcp cell update:
    // sig(f)*c + sig(i)tanh(g) = [c*d1 + s*t3] / (t3*d1), d1=(1+ei)(1+eg), t3=1+ef,
    // s=2log2e*(eg-1) so cst is in exp2 units and ec = e2(cc) directly. 7 trans/element.
    auto epi = [&](const floatx4& Gi, const floatx4& Gf, const floatx4& Gg,
                   const floatx4& Go, int rg, unsigned short* hn) {
#pragma unroll
        for (int r = 0; r < 4; ++r) {
            float ei = e2_(-Gi[r]);
            float eg = e2_(Gg[r]);
            float ef = e2_(-Gf[r]);
            float t1 = 1.f + ei;
            float d1 = fmaf(t1, eg, t1);             // (1+ei)(1+eg)
            float t3 = 1.f + ef;
            float s  = fmaf(LOG2E2, eg, -LOG2E2);    // 2log2e*(eg-1)
            float num = fmaf(cst[rg][r], d1, s * t3);
            float cc = num * rcp_(t3 * d1);          // cell state, exp2 units
            cst[rg][r] = cc;
            float eo = e2_(-Go[r]);
            float ec = e2_(cc);
            float t2 = 1.f + eo;
            float hv = (ec - 1.f) * rcp_(fmaf(t2, ec, t2));
            if (wr)
                hn[(rg * 16 + 4 * q + r) * KP + jcol] = f2bf(hv);
        }
    };

    // ---- Phase 1: LSTM1, 30 steps, 1 barrier/step; t-loop unrolled x2 (fixed buffers) ----
    // Per rg: load af, one 16-MFMA burst (4 independent chains), then the trans epilogue.
    auto cell1 = [&](const unsigned short* __restrict__ hc,
                     unsigned short* __restrict__ hn, int t) {
        if (wave == 7) {
            // K-slot maintenance: hn[.,100] = x_{t+1}, hn[.,101] = 1.0
            int tn = (t < Tn - 1) ? t + 1 : t;
            int row = lane & 31;
            float xv = xl[tn * ROWS + row];
            unsigned short val = (lane < 32) ? f2bf(xv) : (unsigned short)0x3F80;
            hn[row * KP + 100 + (lane >> 5)] = val;
        } else {
#pragma unroll
            for (int rg = 0; rg < RGn; ++rg) {
                short8 af[4];   // A[m=l][k=kt*32+q*8+j], rows rg*16+m
#pragma unroll
                for (int kt = 0; kt < 4; ++kt)
                    af[kt] = *(const short8*)(hc + (rg * 16 + l) * KP + kt * 32 + q * 8);
                floatx4 A0, A1, A2, A3;   // gates i, f, g, o
                A0 = MFMA(af[0], bf[0][0], zro, 0, 0, 0);
                A1 = MFMA(af[0], bf[1][0], zro, 0, 0, 0);
                A2 = MFMA(af[0], bf[2][0], zro, 0, 0, 0);
                A3 = MFMA(af[0], bf[3][0], zro, 0, 0, 0);
#pragma unroll
                for (int kt = 1; kt < 4; ++kt) {
                    A0 = MFMA(af[kt], bf[0][kt], A0, 0, 0, 0);
                    A1 = MFMA(af[kt], bf[1][kt], A1, 0, 0, 0);
                    A2 = MFMA(af[kt], bf[2][kt], A2, 0, 0, 0);
                    A3 = MFMA(af[kt], bf[3][kt], A3, 0, 0, 0);
                }
                epi(A0, A1, A2, A3, rg, hn);
            }
        }
    };
    for (int tt = 0; tt < Tn; tt += 2) {
        cell1(hb0, hb1, tt);
        __syncthreads();
        cell1(hb1, hb0, tt + 1);
        __syncthreads();
    }

    // ---- Wih2 frags; gin2 = (bih2+bhh2 fold) + last·Wih2^T parked in LDS (scaled units) ----
    if (wave < 7) {
        const short8* fr = (const short8*)((const char*)ws + FRAG_BYTES);
#pragma unroll
        for (int G = 0; G < 4; ++G)
#pragma unroll
            for (int kt = 0; kt < 4; ++kt)
                bf[G][kt] = fr[((((G << 3) | wave) << 2) + kt) * 64 + lane];
        const unsigned short* hl = hb0;   // last = h after t=29 (t=29 odd -> hn was hb0)
        // hl K-slots: 100 = stale x (Wih2 row 100 is zero -> harmless), 101 = 1.0 (bias fold)
#pragma unroll
        for (int rg = 0; rg < RGn; ++rg) {
            short8 af[4];
#pragma unroll
            for (int kt = 0; kt < 4; ++kt)
                af[kt] = *(const short8*)(hl + (rg * 16 + l) * KP + kt * 32 + q * 8);
            floatx4 acc[4];
#pragma unroll
            for (int G = 0; G < 4; ++G)
                acc[G] = MFMA(af[0], bf[G][0], zro, 0, 0, 0);
#pragma unroll
            for (int kt = 1; kt < 4; ++kt)
#pragma unroll
                for (int G = 0; G < 4; ++G)
                    acc[G] = MFMA(af[kt], bf[G][kt], acc[G], 0, 0, 0);
#pragma unroll
            for (int G = 0; G < 4; ++G) {
                int n = G * 128 + jcol;
                uint2 pk;
                pk.x = (unsigned)f2bf(acc[G][0]) | ((unsigned)f2bf(acc[G][1]) << 16);
                pk.y = (unsigned)f2bf(acc[G][2]) | ((unsigned)f2bf(acc[G][3]) << 16);
                *(uint2*)(g2 + n * RP + rg * 16 + 4 * q) = pk;   // same wave reads it back
            }
        }
        // ---- Whh2 frags ----
        const short8* fr2 = (const short8*)((const char*)ws + 2 * FRAG_BYTES);
#pragma unroll
        for (int G = 0; G < 4; ++G)
#pragma unroll
            for (int kt = 0; kt < 4; ++kt)
                bf[G][kt] = fr2[((((G << 3) | wave) << 2) + kt) * 64 + lane];
    }

    // ---- Phase 2: LSTM2, 7 steps; FC2 runs on wave 7 ----
    // K-slots 100/101 retain phase-1 values (101=1.0 feeds bias folds; 100=stale x hits zero
    // weight rows). Pad cols: zero preacts -> hv=0 (garbage-free as in phase 1).
    const short8* w2fr = (const short8*)((const char*)ws + WS_W2_OFF);
    floatx4 yfc[RGn];
    if (wave == 7) {
#pragma unroll
        for (int rg = 0; rg < RGn; ++rg) yfc[rg] = zro;
    }

    for (int ps = 0; ps < Pn; ++ps) {
        int t = Tn + ps;
        const unsigned short* hc = (t & 1) ? hb1 : hb0;
        unsigned short* hn = (t & 1) ? hb0 : hb1;
        if (wave == 7) {
            if (ps >= 1) {   // hc holds h2 of step ps-1
                short8 w2f[4];
#pragma unroll
                for (int kt = 0; kt < 4; ++kt)
                    w2f[kt] = w2fr[((ps - 1) * 4 + kt) * 64 + lane];
#pragma unroll
                for (int rg = 0; rg < RGn; ++rg) {
                    short8 af2[4];
#pragma unroll
                    for (int kt = 0; kt < 4; ++kt)
                        af2[kt] = *(const short8*)(hc + (rg * 16 + l) * KP + kt * 32 + q * 8);
#pragma unroll
                    for (int kt = 0; kt < 4; ++kt)
                        yfc[rg] = MFMA(af2[kt], w2f[kt], yfc[rg], 0, 0, 0);
                }
            }
        } else {
#pragma unroll
            for (int rg = 0; rg < RGn; ++rg) {
                short8 af[4];
#pragma unroll
                for (int kt = 0; kt < 4; ++kt)
                    af[kt] = *(const short8*)(hc + (rg * 16 + l) * KP + kt * 32 + q * 8);
                floatx4 A0, A1, A2, A3;   // gates i, f, g, o; C-in = gin2
                {
                    uint2 p0 = *(const uint2*)(g2 + (0 * 128 + jcol) * RP + rg * 16 + 4 * q);
                    uint2 p1 = *(const uint2*)(g2 + (1 * 128 + jcol) * RP + rg * 16 + 4 * q);
                    uint2 p2 = *(const uint2*)(g2 + (2 * 128 + jcol) * RP + rg * 16 + 4 * q);
                    uint2 p3 = *(const uint2*)(g2 + (3 * 128 + jcol) * RP + rg * 16 + 4 * q);
                    A0[0] = __uint_as_float(p0.x << 16);
                    A0[1] = __uint_as_float(p0.x & 0xFFFF0000u);
                    A0[2] = __uint_as_float(p0.y << 16);
                    A0[3] = __uint_as_float(p0.y & 0xFFFF0000u);
                    A1[0] = __uint_as_float(p1.x << 16);
                    A1[1] = __uint_as_float(p1.x & 0xFFFF0000u);
                    A1[2] = __uint_as_float(p1.y << 16);
                    A1[3] = __uint_as_float(p1.y & 0xFFFF0000u);
                    A2[0] = __uint_as_float(p2.x << 16);
                    A2[1] = __uint_as_float(p2.x & 0xFFFF0000u);
                    A2[2] = __uint_as_float(p2.y << 16);
                    A2[3] = __uint_as_float(p2.y & 0xFFFF0000u);
                    A3[0] = __uint_as_float(p3.x << 16);
                    A3[1] = __uint_as_float(p3.x & 0xFFFF0000u);
                    A3[2] = __uint_as_float(p3.y << 16);
                    A3[3] = __uint_as_float(p3.y & 0xFFFF0000u);
                }
#pragma unroll
                for (int kt = 0; kt < 4; ++kt) {
                    A0 = MFMA(af[kt], bf[0][kt], A0, 0, 0, 0);
                    A1 = MFMA(af[kt], bf[1][kt], A1, 0, 0, 0);
                    A2 = MFMA(af[kt], bf[2][kt], A2, 0, 0, 0);
                    A3 = MFMA(af[kt], bf[3][kt], A3, 0, 0, 0);
                }
                epi(A0, A1, A2, A3, rg, hn);   // ps=6 store feeds final FC2
            }
        }
        __syncthreads();
    }

    // ---- final FC2 for h2 of ps=6 (t=36 even -> hn=hb1); b2 folded (scaled) into ps=6 k=101 ----
    if (wave == 7) {
        short8 w2f[4];
#pragma unroll
        for (int kt = 0; kt < 4; ++kt)
            w2f[kt] = w2fr[(6 * 4 + kt) * 64 + lane];
#pragma unroll
        for (int rg = 0; rg < RGn; ++rg) {
            short8 af2[4];
#pragma unroll
            for (int kt = 0; kt < 4; ++kt)
                af2[kt] = *(const short8*)(hb1 + (rg * 16 + l) * KP + kt * 32 + q * 8);
#pragma unroll
            for (int kt = 0; kt < 4; ++kt)
                yfc[rg] = MFMA(af2[kt], w2f[kt], yfc[rg], 0, 0, 0);
            if (l < Pn) {
#pragma unroll
                for (int r = 0; r < 4; ++r)   // y is log2e-scaled: sig = 1/(1+2^-y')
                    out[(rowbase + rg * 16 + 4 * q + r) * Pn + l] =
                        rcp_(1.f + e2_(-yfc[rg][r]));
            }
        }
    }
}

extern "C" void kernel_launch(void* const* d_in, const int* in_sizes, int n_in,
                              void* d_out, int out_size, void* d_ws, size_t ws_size,
                              hipStream_t stream) {
    const float* x    = (const float*)d_in[0];
    const float* W1   = (const float*)d_in[1];
    const float* b1   = (const float*)d_in[2];
    const float* Wih1 = (const float*)d_in[3];
    const float* Whh1 = (const float*)d_in[4];
    const float* bih1 = (const float*)d_in[5];
    const float* bhh1 = (const float*)d_in[6];
    const float* Wih2 = (const float*)d_in[7];
    const float* Whh2 = (const float*)d_in[8];
    const float* bih2 = (const float*)d_in[9];
    const float* bhh2 = (const float*)d_in[10];
    const float* W2   = (const float*)d_in[11];
    const float* b2   = (const float*)d_in[12];
    float* out = (float*)d_out;
    float* ws  = (float*)d_ws;

    (void)hipFuncSetAttribute((const void*)lstm_fused,
                              hipFuncAttributeMaxDynamicSharedMemorySize, SMEM_BYTES);

    setup_kernel<<<PACK_BLOCKS, 256, 0, stream>>>(W1, b1, Wih1, bih1, bhh1,
                                                  bih2, bhh2, Whh1, Wih2, Whh2, W2, b2, ws);
    lstm_fused<<<Bn / ROWS, 512, SMEM_BYTES, stream>>>(x, ws, out);
}

// Round 13
// 174.028 us; speedup vs baseline: 1.1269x; 1.0071x over previous
//
#include <hip/hip_runtime.h>
#include <math.h>

// Problem constants
#define Tn 30
#define Bn 16384
#define Hn 100
#define Pn 7

// Tiling: gates padded 100->128 units => N=512 (32 n-tiles); K padded 100->128 (4 k-tiles of 32).
// K slots 100/101 carry the FC1 fold: A[k=100]=x_t(row), A[k=101]=1.0; Whh1 B rows 100/101 hold
// u1[j]/wc1[j]; Wih2 row 101 holds bih2+bhh2; W2(ps=6) row 101 holds b2.
// Gate weights pre-scaled by log2e (gate g by 2*log2e, W2/b2 by log2e): bare v_exp_f32 (exp2)
// with src-modifier negation. Merged-rcp cell update (7 trans/element, bit-stable).
// ROUND-13: s_setprio(1) around the MFMA bursts. Mechanism: the 2 blocks/CU are NOT mutually
// barrier-synced -> they drift out of phase; a SIMD hosts waves in different phases (one block
// in MFMA burst, the other in trans epilogue). setprio lets MFMA-entering waves preempt
// trans-issuing waves (T5 role-diversity prerequisite present, unlike lockstep GEMM).
// Pre-commit: if flat, the kernel is at its structural plateau (128 regs/wave = 64 arch +
// 64 AGPR bf frags -> 16 waves/CU register ceiling; trans at algebraic min; residual 40%
// stall is recurrence-barrier latency needing more waves to hide).
#define ROWS 32           // rows per block
#define RGn 2             // row-groups of 16
#define KP 136            // h row pitch (ushorts); 272B -> 16B-aligned A-frag reads
#define RP 36             // gin2 row pitch (ushorts): 32 rows + 4 pad
#define NFRAG 128         // B-frags per matrix (32 nt x 4 kt)
#define FRAG_BYTES (NFRAG * 64 * 16)   // 131072 per matrix
#define WS_W2_OFF (3 * FRAG_BYTES)     // 28 W2 frags (7 ps x 4 kt)
#define HBUF_USH (ROWS * KP)           // 4352
#define G2_USH (512 * RP)              // 18432
#define XL_USH_OFF (2 * HBUF_USH + G2_USH)            // 27136 ushorts
#define SMEM_BYTES (XL_USH_OFF * 2 + Tn * ROWS * 4)   // 54272 + 3840 = 58112

#define PACK_BLOCKS 103   // (3*128*64 + 28*64)/256 exactly

#define LOG2E 1.4426950408889634f
#define LOG2E2 2.8853900817779268f   // 2*log2e

typedef __attribute__((ext_vector_type(8))) short short8;   // 8 bf16 (4 VGPRs)
typedef __attribute__((ext_vector_type(4))) float floatx4;  // MFMA C/D

__device__ __forceinline__ float rcp_(float v) { return __builtin_amdgcn_rcpf(v); }
__device__ __forceinline__ float e2_(float v) { return __builtin_amdgcn_exp2f(v); }
__device__ __forceinline__ unsigned short f2bf(float v) {
    unsigned int u = __float_as_uint(v);
    return (unsigned short)((u + 0x7FFFu + ((u >> 16) & 1u)) >> 16);   // RNE
}
#define MFMA __builtin_amdgcn_mfma_f32_16x16x32_bf16

// Pack the 3 recurrent matrices (400x100) into bf16 B-frag layout (gates padded to 128 units),
// with the bias/FC1 folds in padded K rows, ALL PRE-SCALED: gates i,f,o by log2e; gate g (G==2)
// by 2*log2e; W2/b2 by log2e. Folds:
//   mat 0 (Whh1): k=100 -> u1[j] = Wih1[j,:]·W1 ; k=101 -> wc1[j] = Wih1[j,:]·b1 + bih1[j] + bhh1[j]
//   mat 1 (Wih2): k=101 -> bih2[j] + bhh2[j]
//   W2 frags:     k=101 && ps==6 -> b2[p]   (A k=101 is 1.0 every step; add bias exactly once)
// B[k][n]: n = lane&15, k = (lane>>4)*8 + jj  (16x16x32 bf16 B mapping, HW-verified).
__global__ void setup_kernel(const float* __restrict__ W1,
                             const float* __restrict__ b1,
                             const float* __restrict__ Wih1,
                             const float* __restrict__ bih1,
                             const float* __restrict__ bhh1,
                             const float* __restrict__ bih2,
                             const float* __restrict__ bhh2,
                             const float* __restrict__ Whh1,
                             const float* __restrict__ Wih2,
                             const float* __restrict__ Whh2,
                             const float* __restrict__ W2,
                             const float* __restrict__ b2,
                             float* __restrict__ ws) {
    int gid = blockIdx.x * 256 + threadIdx.x;   // 3*128*64 + 28*64 = 26368
    int lane = gid & 63;
    int l = lane & 15, q = lane >> 4;
    unsigned short hh[8];
    uint4 u;
    if (gid < 3 * NFRAG * 64) {
        int mat = gid / (NFRAG * 64);
        int f = (gid % (NFRAG * 64)) >> 6;
        int nt = f >> 2, kt = f & 3;
        int G = nt >> 3, ag = nt & 7;
        int j = ag * 16 + l;                    // unit within gate
        int row = G * Hn + (j < Hn ? j : 0);    // row of the 400-row weight matrices
        const float sG = (G == 2) ? LOG2E2 : LOG2E;   // exp2 pre-scale (g gate carries the 2x)
        const float* W = (mat == 0) ? Whh1 : (mat == 1) ? Wih2 : Whh2;
        const float* wrow = W + row * Hn;
        float u1 = 0.f, wc1 = 0.f;
        if (mat == 0 && kt == 3 && q == 0 && j < Hn) {   // lanes producing k=100/101
            for (int k = 0; k < Hn; ++k) {
                float a = Wih1[row * Hn + k];
                u1 += a * W1[k];
                wc1 += a * b1[k];
            }
            wc1 += bih1[row] + bhh1[row];
        }
        int kbase = kt * 32 + q * 8;
#pragma unroll
        for (int jj = 0; jj < 8; ++jj) {
            int k = kbase + jj;
            unsigned short v = 0;
            if (j < Hn) {
                if (k < Hn) v = f2bf(wrow[k] * sG);
                else if (mat == 0 && k == 100) v = f2bf(u1 * sG);
                else if (mat == 0 && k == 101) v = f2bf(wc1 * sG);
                else if (mat == 1 && k == 101) v = f2bf((bih2[row] + bhh2[row]) * sG);
            }
            hh[jj] = v;
        }
        u.x = (unsigned)hh[0] | ((unsigned)hh[1] << 16);
        u.y = (unsigned)hh[2] | ((unsigned)hh[3] << 16);
        u.z = (unsigned)hh[4] | ((unsigned)hh[5] << 16);
        u.w = (unsigned)hh[6] | ((unsigned)hh[7] << 16);
        ((uint4*)((char*)ws + mat * FRAG_BYTES))[f * 64 + lane] = u;
    } else {
        int t = gid - 3 * NFRAG * 64;           // 0..1791
        int f = t >> 6;                         // 0..27 = ps*4 + kt
        int ps = f >> 2, kt = f & 3;
        int kbase = kt * 32 + q * 8;
#pragma unroll
        for (int jj = 0; jj < 8; ++jj) {
            int k = kbase + jj;
            unsigned short v = 0;
            if (l < Pn) {
                if (k < Hn) v = f2bf(W2[l * (Pn * Hn) + ps * Hn + k] * LOG2E);
                else if (k == 101 && ps == 6) v = f2bf(b2[l] * LOG2E);
            }
            hh[jj] = v;
        }
        u.x = (unsigned)hh[0] | ((unsigned)hh[1] << 16);
        u.y = (unsigned)hh[2] | ((unsigned)hh[3] << 16);
        u.z = (unsigned)hh[4] | ((unsigned)hh[5] << 16);
        u.w = (unsigned)hh[6] | ((unsigned)hh[7] << 16);
        ((uint4*)((char*)ws + WS_W2_OFF))[f * 64 + lane] = u;
    }
}

__global__ __launch_bounds__(512, 4) void lstm_fused(
    const float* __restrict__ x,     // (T,B)
    const float* __restrict__ ws,    // packed frags (+folds), exp2-prescaled
    float* __restrict__ out)         // (B,7)
{
    extern __shared__ unsigned short sm[];
    unsigned short* hb0 = sm;                   // h double buffer [row ROWS][k KP]
    unsigned short* hb1 = sm + HBUF_USH;
    unsigned short* g2 = sm + 2 * HBUF_USH;     // gin2 bf16 [n 512][row RP] (scaled units)
    float* xl = (float*)(sm + XL_USH_OFF);      // x slice [t 30][row 32]

    const int tid = threadIdx.x;
    const int wave = tid >> 6, lane = tid & 63;
    const int l = lane & 15, q = lane >> 4;
    const int jcol = wave * 16 + l;             // this wave's unit column (0..127)
    const int rowbase = blockIdx.x * ROWS;
    // store predicate: waves 0-5 all-real; wave 6 must preserve cols 100/101 (x / 1.0 slots);
    // pad cols 102..111 take hv which is exactly 0 there (zero B cols -> zero preacts).
    const bool wr = (wave != 6) || (l < 4) || (l >= 6);

    for (int i = tid; i < 2 * HBUF_USH; i += 512) sm[i] = 0;
    for (int i = tid; i < Tn * ROWS; i += 512)
        xl[i] = x[(i >> 5) * Bn + rowbase + (i & 31)];
    __syncthreads();   // zeroing + x staging done before seeding
    if (tid < ROWS) {
        hb0[tid * KP + 100] = f2bf(x[rowbase + tid]);   // x_0 in K slot 100
        hb0[tid * KP + 101] = (unsigned short)0x3F80;   // 1.0 in K slot 101
    }

    // this wave's 16 Whh1 B-frags -> registers (held for all 30 steps; AGPR-resident)
    short8 bf[4][4];   // [G][kt]
    floatx4 cst[RGn];  // cell state (exp2 units: cc = c * 2log2e), rows 4q+r, unit jcol
    const floatx4 zro = (floatx4){0.f, 0.f, 0.f, 0.f};
    if (wave < 7) {
        const short8* fr = (const short8*)ws;
#pragma unroll
        for (int G = 0; G < 4; ++G)
#pragma unroll
            for (int kt = 0; kt < 4; ++kt)
                bf[G][kt] = fr[((((G << 3) | wave) << 2) + kt) * 64 + lane];
#pragma unroll
        for (int rg = 0; rg < RGn; ++rg) cst[rg] = zro;
    }
    __syncthreads();   // h buffers ready (zero + seed)

    // Epilogue: gates exp2-scaled (i',f',o' = v*log2e; g' = v*2log2e). Merged-rcp cell update:
    // sig(f)*c + sig(i)tanh(g) = [c*d1 + s*t3] / (t3*d1), d1=(1+ei)(1+eg), t3=1+ef,
    // s=2log2e*(eg-1) so cst is in exp2 units and ec = e2(cc) directly. 7 trans/element.
    auto epi = [&](const floatx4& Gi, const floatx4& Gf, const floatx4& Gg,
                   const floatx4& Go, int rg, unsigned short* hn) {
#pragma unroll
        for (int r = 0; r < 4; ++r) {
            float ei = e2_(-Gi[r]);
            float eg = e2_(Gg[r]);
            float ef = e2_(-Gf[r]);
            float t1 = 1.f + ei;
            float d1 = fmaf(t1, eg, t1);             // (1+ei)(1+eg)
            float t3 = 1.f + ef;
            float s  = fmaf(LOG2E2, eg, -LOG2E2);    // 2log2e*(eg-1)
            float num = fmaf(cst[rg][r], d1, s * t3);
            float cc = num * rcp_(t3 * d1);          // cell state, exp2 units
            cst[rg][r] = cc;
            float eo = e2_(-Go[r]);
            float ec = e2_(cc);
            float t2 = 1.f + eo;
            float hv = (ec - 1.f) * rcp_(fmaf(t2, ec, t2));
            if (wr)
                hn[(rg * 16 + 4 * q + r) * KP + jcol] = f2bf(hv);
        }
    };

    // ---- Phase 1: LSTM1, 30 steps, 1 barrier/step; t-loop unrolled x2 (fixed buffers) ----
    // Per rg: load af, one 16-MFMA burst (4 independent chains) under setprio(1), epilogue.
    auto cell1 = [&](const unsigned short* __restrict__ hc,
                     unsigned short* __restrict__ hn, int t) {
        if (wave == 7) {
            // K-slot maintenance: hn[.,100] = x_{t+1}, hn[.,101] = 1.0
            int tn = (t < Tn - 1) ? t + 1 : t;
            int row = lane & 31;
            float xv = xl[tn * ROWS + row];
            unsigned short val = (lane < 32) ? f2bf(xv) : (unsigned short)0x3F80;
            hn[row * KP + 100 + (lane >> 5)] = val;
        } else {
#pragma unroll
            for (int rg = 0; rg < RGn; ++rg) {
                short8 af[4];   // A[m=l][k=kt*32+q*8+j], rows rg*16+m
#pragma unroll
                for (int kt = 0; kt < 4; ++kt)
                    af[kt] = *(const short8*)(hc + (rg * 16 + l) * KP + kt * 32 + q * 8);
                floatx4 A0, A1, A2, A3;   // gates i, f, g, o
                __builtin_amdgcn_s_setprio(1);
                A0 = MFMA(af[0], bf[0][0], zro, 0, 0, 0);
                A1 = MFMA(af[0], bf[1][0], zro, 0, 0, 0);
                A2 = MFMA(af[0], bf[2][0], zro, 0, 0, 0);
                A3 = MFMA(af[0], bf[3][0], zro, 0, 0, 0);
#pragma unroll
                for (int kt = 1; kt < 4; ++kt) {
                    A0 = MFMA(af[kt], bf[0][kt], A0, 0, 0, 0);
                    A1 = MFMA(af[kt], bf[1][kt], A1, 0, 0, 0);
                    A2 = MFMA(af[kt], bf[2][kt], A2, 0, 0, 0);
                    A3 = MFMA(af[kt], bf[3][kt], A3, 0, 0, 0);
                }
                __builtin_amdgcn_s_setprio(0);
                epi(A0, A1, A2, A3, rg, hn);
            }
        }
    };
    for (int tt = 0; tt < Tn; tt += 2) {
        cell1(hb0, hb1, tt);
        __syncthreads();
        cell1(hb1, hb0, tt + 1);
        __syncthreads();
    }

    // ---- Wih2 frags; gin2 = (bih2+bhh2 fold) + last·Wih2^T parked in LDS (scaled units) ----
    if (wave < 7) {
        const short8* fr = (const short8*)((const char*)ws + FRAG_BYTES);
#pragma unroll
        for (int G = 0; G < 4; ++G)
#pragma unroll
            for (int kt = 0; kt < 4; ++kt)
                bf[G][kt] = fr[((((G << 3) | wave) << 2) + kt) * 64 + lane];
        const unsigned short* hl = hb0;   // last = h after t=29 (t=29 odd -> hn was hb0)
        // hl K-slots: 100 = stale x (Wih2 row 100 is zero -> harmless), 101 = 1.0 (bias fold)
#pragma unroll
        for (int rg = 0; rg < RGn; ++rg) {
            short8 af[4];
#pragma unroll
            for (int kt = 0; kt < 4; ++kt)
                af[kt] = *(const short8*)(hl + (rg * 16 + l) * KP + kt * 32 + q * 8);
            floatx4 acc[4];
#pragma unroll
            for (int G = 0; G < 4; ++G)
                acc[G] = MFMA(af[0], bf[G][0], zro, 0, 0, 0);
#pragma unroll
            for (int kt = 1; kt < 4; ++kt)
#pragma unroll
                for (int G = 0; G < 4; ++G)
                    acc[G] = MFMA(af[kt], bf[G][kt], acc[G], 0, 0, 0);
#pragma unroll
            for (int G = 0; G < 4; ++G) {
                int n = G * 128 + jcol;
                uint2 pk;
                pk.x = (unsigned)f2bf(acc[G][0]) | ((unsigned)f2bf(acc[G][1]) << 16);
                pk.y = (unsigned)f2bf(acc[G][2]) | ((unsigned)f2bf(acc[G][3]) << 16);
                *(uint2*)(g2 + n * RP + rg * 16 + 4 * q) = pk;   // same wave reads it back
            }
        }
        // ---- Whh2 frags ----
        const short8* fr2 = (const short8*)((const char*)ws + 2 * FRAG_BYTES);
#pragma unroll
        for (int G = 0; G < 4; ++G)
#pragma unroll
            for (int kt = 0; kt < 4; ++kt)
                bf[G][kt] = fr2[((((G << 3) | wave) << 2) + kt) * 64 + lane];
    }

    // ---- Phase 2: LSTM2, 7 steps; FC2 runs on wave 7 ----
    // K-slots 100/101 retain phase-1 values (101=1.0 feeds bias folds; 100=stale x hits zero
    // weight rows). Pad cols: zero preacts -> hv=0 (garbage-free as in phase 1).
    const short8* w2fr = (const short8*)((const char*)ws + WS_W2_OFF);
    floatx4 yfc[RGn];
    if (wave == 7) {
#pragma unroll
        for (int rg = 0; rg < RGn; ++rg) yfc[rg] = zro;
    }

    for (int ps = 0; ps < Pn; ++ps) {
        int t = Tn + ps;
        const unsigned short* hc = (t & 1) ? hb1 : hb0;
        unsigned short* hn = (t & 1) ? hb0 : hb1;
        if (wave == 7) {
            if (ps >= 1) {   // hc holds h2 of step ps-1
                short8 w2f[4];
#pragma unroll
                for (int kt = 0; kt < 4; ++kt)
                    w2f[kt] = w2fr[((ps - 1) * 4 + kt) * 64 + lane];
#pragma unroll
                for (int rg = 0; rg < RGn; ++rg) {
                    short8 af2[4];
#pragma unroll
                    for (int kt = 0; kt < 4; ++kt)
                        af2[kt] = *(const short8*)(hc + (rg * 16 + l) * KP + kt * 32 + q * 8);
#pragma unroll
                    for (int kt = 0; kt < 4; ++kt)
                        yfc[rg] = MFMA(af2[kt], w2f[kt], yfc[rg], 0, 0, 0);
                }
            }
        } else {
#pragma unroll
            for (int rg = 0; rg < RGn; ++rg) {
                short8 af[4];
#pragma unroll
                for (int kt = 0; kt < 4; ++kt)
                    af[kt] = *(const short8*)(hc + (rg * 16 + l) * KP + kt * 32 + q * 8);
                floatx4 A0, A1, A2, A3;   // gates i, f, g, o; C-in = gin2
                {
                    uint2 p0 = *(const uint2*)(g2 + (0 * 128 + jcol) * RP + rg * 16 + 4 * q);
                    uint2 p1 = *(const uint2*)(g2 + (1 * 128 + jcol) * RP + rg * 16 + 4 * q);
                    uint2 p2 = *(const uint2*)(g2 + (2 * 128 + jcol) * RP + rg * 16 + 4 * q);
                    uint2 p3 = *(const uint2*)(g2 + (3 * 128 + jcol) * RP + rg * 16 + 4 * q);
                    A0[0] = __uint_as_float(p0.x << 16);
                    A0[1] = __uint_as_float(p0.x & 0xFFFF0000u);
                    A0[2] = __uint_as_float(p0.y << 16);
                    A0[3] = __uint_as_float(p0.y & 0xFFFF0000u);
                    A1[0] = __uint_as_float(p1.x << 16);
                    A1[1] = __uint_as_float(p1.x & 0xFFFF0000u);
                    A1[2] = __uint_as_float(p1.y << 16);
                    A1[3] = __uint_as_float(p1.y & 0xFFFF0000u);
                    A2[0] = __uint_as_float(p2.x << 16);
                    A2[1] = __uint_as_float(p2.x & 0xFFFF0000u);
                    A2[2] = __uint_as_float(p2.y << 16);
                    A2[3] = __uint_as_float(p2.y & 0xFFFF0000u);
                    A3[0] = __uint_as_float(p3.x << 16);
                    A3[1] = __uint_as_float(p3.x & 0xFFFF0000u);
                    A3[2] = __uint_as_float(p3.y << 16);
                    A3[3] = __uint_as_float(p3.y & 0xFFFF0000u);
                }
                __builtin_amdgcn_s_setprio(1);
#pragma unroll
                for (int kt = 0; kt < 4; ++kt) {
                    A0 = MFMA(af[kt], bf[0][kt], A0, 0, 0, 0);
                    A1 = MFMA(af[kt], bf[1][kt], A1, 0, 0, 0);
                    A2 = MFMA(af[kt], bf[2][kt], A2, 0, 0, 0);
                    A3 = MFMA(af[kt], bf[3][kt], A3, 0, 0, 0);
                }
                __builtin_amdgcn_s_setprio(0);
                epi(A0, A1, A2, A3, rg, hn);   // ps=6 store feeds final FC2
            }
        }
        __syncthreads();
    }

    // ---- final FC2 for h2 of ps=6 (t=36 even -> hn=hb1); b2 folded (scaled) into ps=6 k=101 ----
    if (wave == 7) {
        short8 w2f[4];
#pragma unroll
        for (int kt = 0; kt < 4; ++kt)
            w2f[kt] = w2fr[(6 * 4 + kt) * 64 + lane];
#pragma unroll
        for (int rg = 0; rg < RGn; ++rg) {
            short8 af2[4];
#pragma unroll
            for (int kt = 0; kt < 4; ++kt)
                af2[kt] = *(const short8*)(hb1 + (rg * 16 + l) * KP + kt * 32 + q * 8);
#pragma unroll
            for (int kt = 0; kt < 4; ++kt)
                yfc[rg] = MFMA(af2[kt], w2f[kt], yfc[rg], 0, 0, 0);
            if (l < Pn) {
#pragma unroll
                for (int r = 0; r < 4; ++r)   // y is log2e-scaled: sig = 1/(1+2^-y')
                    out[(rowbase + rg * 16 + 4 * q + r) * Pn + l] =
                        rcp_(1.f + e2_(-yfc[rg][r]));
            }
        }
    }
}

extern "C" void kernel_launch(void* const* d_in, const int* in_sizes, int n_in,
                              void* d_out, int out_size, void* d_ws, size_t ws_size,
                              hipStream_t stream) {
    const float* x    = (const float*)d_in[0];
    const float* W1   = (const float*)d_in[1];
    const float* b1   = (const float*)d_in[2];
    const float* Wih1 = (const float*)d_in[3];
    const float* Whh1 = (const float*)d_in[4];
    const float* bih1 = (const float*)d_in[5];
    const float* bhh1 = (const float*)d_in[6];
    const float* Wih2 = (const float*)d_in[7];
    const float* Whh2 = (const float*)d_in[8];
    const float* bih2 = (const float*)d_in[9];
    const float* bhh2 = (const float*)d_in[10];
    const float* W2   = (const float*)d_in[11];
    const float* b2   = (const float*)d_in[12];
    float* out = (float*)d_out;
    float* ws  = (float*)d_ws;

    (void)hipFuncSetAttribute((const void*)lstm_fused,
                              hipFuncAttributeMaxDynamicSharedMemorySize, SMEM_BYTES);

    setup_kernel<<<PACK_BLOCKS, 256, 0, stream>>>(W1, b1, Wih1, bih1, bhh1,
                                                  bih2, bhh2, Whh1, Wih2, Whh2, W2, b2, ws);
    lstm_fused<<<Bn / ROWS, 512, SMEM_BYTES, stream>>>(x, ws, out);
}